// Round 3
// baseline (513.321 us; speedup 1.0000x reference)
//
#include <hip/hip_runtime.h>
#include <hip/hip_bf16.h>

#define NN 8192
#define DD 128
#define CC 10
#define TT 1024

typedef __attribute__((ext_vector_type(8))) short bf16x8;   // 8 bf16 in 4 VGPRs
typedef __attribute__((ext_vector_type(4))) float f32x4;

// ---------------- K1: class head + softmax + coefficients + s^T (f32 in, bf16 sT out) ----
// one wave per node
__global__ __launch_bounds__(256) void k_head(
    const float* __restrict__ xr, const float* __restrict__ xi,
    const float* __restrict__ Wcr, const float* __restrict__ bcr,
    const float* __restrict__ Wci, const float* __restrict__ bci,
    const float* __restrict__ thr, const float* __restrict__ thi,
    const int* __restrict__ labels,
    __hip_bfloat16* __restrict__ sT,      // [256][8192] bf16
    float* __restrict__ stats)            // [8192][4] = inr, ini, picked, lse
{
  const int lane = threadIdx.x & 63;
  const int i = blockIdx.x * 4 + (threadIdx.x >> 6);

  const float xr0 = xr[(size_t)i * DD + lane];
  const float xr1 = xr[(size_t)i * DD + 64 + lane];
  const float xi0 = xi[(size_t)i * DD + lane];
  const float xi1 = xi[(size_t)i * DD + 64 + lane];

  float pn[CC];
#pragma unroll
  for (int c = 0; c < CC; c++) {
    const float wr0 = Wcr[c * DD + lane];
    const float wr1 = Wcr[c * DD + 64 + lane];
    const float wi0 = Wci[c * DD + lane];
    const float wi1 = Wci[c * DD + 64 + lane];
    float pa = xr0 * wr0 + xr1 * wr1;   // xr . Wc_r[c]
    float pb = xi0 * wr0 + xi1 * wr1;   // xi . Wc_r[c]
    float pc = xi0 * wi0 + xi1 * wi1;   // xi . Wc_i[c]
    float pd = xr0 * wi0 + xr1 * wi1;   // xr . Wc_i[c]
#pragma unroll
    for (int off = 32; off > 0; off >>= 1) {
      pa += __shfl_xor(pa, off, 64);
      pb += __shfl_xor(pb, off, 64);
      pc += __shfl_xor(pc, off, 64);
      pd += __shfl_xor(pd, off, 64);
    }
    const float cr = (pa + bcr[c]) - (pc + bci[c]);
    const float ci = (pb + bcr[c]) + (pd + bci[c]);
    pn[c] = sqrtf(cr * cr + ci * ci);
  }
  float mx = pn[0];
#pragma unroll
  for (int c = 1; c < CC; c++) mx = fmaxf(mx, pn[c]);
  float ex[CC];
  float den = 0.f;
#pragma unroll
  for (int c = 0; c < CC; c++) { ex[c] = expf(pn[c] - mx); den += ex[c]; }
  float inr = 0.f, ini = 0.f;
#pragma unroll
  for (int c = 0; c < CC; c++) {
    const float sm = ex[c] / den;
    inr += sm * thr[c];
    ini += sm * thi[c];
  }
  // out = conj(in):  s_r = in_r*xr + in_i*xi ; s_i = in_r*xi - in_i*xr
  sT[(size_t)(lane)       * NN + i] = __float2bfloat16(inr * xr0 + ini * xi0);
  sT[(size_t)(lane + 64)  * NN + i] = __float2bfloat16(inr * xr1 + ini * xi1);
  sT[(size_t)(lane + 128) * NN + i] = __float2bfloat16(inr * xi0 - ini * xr0);
  sT[(size_t)(lane + 192) * NN + i] = __float2bfloat16(inr * xi1 - ini * xr1);

  if (lane == 0) {
    const int lab = labels[i];
    float picked = pn[0];
#pragma unroll
    for (int c = 1; c < CC; c++) picked = (lab == c) ? pn[c] : picked;
    stats[i * 4 + 0] = inr;
    stats[i * 4 + 1] = ini;
    stats[i * 4 + 2] = picked;
    stats[i * 4 + 3] = mx + logf(den);
  }
}

// ---------------- K2: build combined MLP weight, transposed, bf16 ----------------
// BT[n][k]: n<128 -> yr col n: [W_r[n][k] | -W_i[n][k-128]]
//           n>=128 -> yi col n-128: [W_i[n-128][k] | W_r[n-128][k-128]]
__global__ __launch_bounds__(256) void k_build_bt(
    const float* __restrict__ Wr, const float* __restrict__ Wi,
    __hip_bfloat16* __restrict__ BT)
{
  const int tid = blockIdx.x * 256 + threadIdx.x;  // 65536
  const int n = tid >> 8, k = tid & 255;
  float v;
  if (n < 128) {
    v = (k < 128) ? Wr[n * 128 + k] : -Wi[n * 128 + (k - 128)];
  } else {
    v = (k < 128) ? Wi[(n - 128) * 128 + k] : Wr[(n - 128) * 128 + (k - 128)];
  }
  BT[tid] = __float2bfloat16(v);
}

// ---------------- K3: m = adj @ s  (split-K MFMA, f32 adj inline-cvt, atomic f32 acc) ----
// block tile 64x256, 4 waves each 64x64; BK=32; grid (128 mtiles, 4 ksplit)
__global__ __launch_bounds__(256) void k_adj_gemm(
    const float* __restrict__ adj,            // [8192][8192] f32
    const __hip_bfloat16* __restrict__ sT,    // [256][8192] bf16
    float* __restrict__ mout)                 // [8192][256] f32, pre-zeroed
{
  __shared__ __align__(16) __hip_bfloat16 As[64 * 32];
  __shared__ __align__(16) __hip_bfloat16 Bs[256 * 32];
  const int t = threadIdx.x;
  const int w = t >> 6;
  const int lane = t & 63;
  const int lm = lane & 15;
  const int kq = lane >> 4;
  const int m0 = blockIdx.x * 64;
  const int kbase = blockIdx.y * 2048;
  const int ar = t >> 2, ac = t & 3;

  f32x4 acc[4][4];
#pragma unroll
  for (int a = 0; a < 4; a++)
#pragma unroll
    for (int b = 0; b < 4; b++) acc[a][b] = (f32x4){0.f, 0.f, 0.f, 0.f};

  for (int kt = 0; kt < 64; kt++) {
    const int k0 = kbase + kt * 32;
    // adj: 8 consecutive f32 per thread -> cvt to bf16 in regs
    const float4 f0 = *(const float4*)(adj + (size_t)(m0 + ar) * NN + k0 + ac * 8);
    const float4 f1 = *(const float4*)(adj + (size_t)(m0 + ar) * NN + k0 + ac * 8 + 4);
    __hip_bfloat16 a16[8] = {
        __float2bfloat16(f0.x), __float2bfloat16(f0.y),
        __float2bfloat16(f0.z), __float2bfloat16(f0.w),
        __float2bfloat16(f1.x), __float2bfloat16(f1.y),
        __float2bfloat16(f1.z), __float2bfloat16(f1.w)};
    bf16x8 b8[4];
#pragma unroll
    for (int q = 0; q < 4; q++) {
      const int idx = q * 256 + t;
      b8[q] = *(const bf16x8*)(sT + (size_t)(idx >> 2) * NN + k0 + (idx & 3) * 8);
    }
    __syncthreads();   // all waves done reading LDS from previous iteration
    *(bf16x8*)((char*)As + t * 16) = *(const bf16x8*)a16;
#pragma unroll
    for (int q = 0; q < 4; q++)
      *(bf16x8*)((char*)Bs + (q * 256 + t) * 16) = b8[q];
    __syncthreads();   // stores visible

    bf16x8 av[4], bv[4];
#pragma unroll
    for (int mt = 0; mt < 4; mt++)
      av[mt] = *(const bf16x8*)&As[(mt * 16 + lm) * 32 + kq * 8];
#pragma unroll
    for (int nt = 0; nt < 4; nt++)
      bv[nt] = *(const bf16x8*)&Bs[(w * 64 + nt * 16 + lm) * 32 + kq * 8];
#pragma unroll
    for (int mt = 0; mt < 4; mt++)
#pragma unroll
      for (int nt = 0; nt < 4; nt++)
        acc[mt][nt] = __builtin_amdgcn_mfma_f32_16x16x32_bf16(av[mt], bv[nt], acc[mt][nt], 0, 0, 0);
  }
  // C/D layout: col = lane&15, row = (lane>>4)*4 + reg  [m89-verified]
#pragma unroll
  for (int mt = 0; mt < 4; mt++)
#pragma unroll
    for (int nt = 0; nt < 4; nt++)
#pragma unroll
      for (int r = 0; r < 4; r++) {
        const int row = m0 + mt * 16 + kq * 4 + r;
        const int col = w * 64 + nt * 16 + lm;
        atomicAdd(&mout[(size_t)row * 256 + col], acc[mt][nt][r]);
      }
}

// ---------------- K4a: msg = in (complex*) m ----------------
__global__ __launch_bounds__(256) void k_msg(
    const float* __restrict__ mbuf, const float* __restrict__ stats,
    __hip_bfloat16* __restrict__ msg)   // [8192][256] = [msg_r | msg_i] bf16
{
  const int tid = blockIdx.x * 256 + threadIdx.x;  // 8192*128
  const int i = tid >> 7, k = tid & 127;
  const float inr = stats[i * 4 + 0], ini = stats[i * 4 + 1];
  const float mr = mbuf[(size_t)i * 256 + k];
  const float mi = mbuf[(size_t)i * 256 + 128 + k];
  msg[(size_t)i * 256 + k]       = __float2bfloat16(inr * mr - ini * mi);
  msg[(size_t)i * 256 + 128 + k] = __float2bfloat16(inr * mi + ini * mr);
}

// ---------------- K4b: MLP GEMM + bias + residual -> out (f32) ----------------
// grid (64 mtiles, 2 col halves); block tile 128x128; K=256
__global__ __launch_bounds__(256) void k_mlp(
    const __hip_bfloat16* __restrict__ msg,  // [8192][256] bf16
    const __hip_bfloat16* __restrict__ BT,   // [256][256] bf16
    const float* __restrict__ br, const float* __restrict__ bi,
    const float* __restrict__ xr, const float* __restrict__ xi,
    float* __restrict__ out)                 // new_r @0, new_i @ NN*DD (f32)
{
  __shared__ __align__(16) __hip_bfloat16 As[128 * 32];
  __shared__ __align__(16) __hip_bfloat16 Bs[128 * 32];
  const int t = threadIdx.x;
  const int w = t >> 6;
  const int lane = t & 63;
  const int lm = lane & 15, kq = lane >> 4;
  const int wr = w >> 1, wc = w & 1;
  const int m0 = blockIdx.x * 128;
  const int by = blockIdx.y;

  f32x4 acc[4][4];
#pragma unroll
  for (int a = 0; a < 4; a++)
#pragma unroll
    for (int b = 0; b < 4; b++) acc[a][b] = (f32x4){0.f, 0.f, 0.f, 0.f};

  for (int kt = 0; kt < 8; kt++) {
    const int k0 = kt * 32;
    bf16x8 a8[2], b8[2];
#pragma unroll
    for (int q = 0; q < 2; q++) {
      const int idx = q * 256 + t;
      a8[q] = *(const bf16x8*)(msg + (size_t)(m0 + (idx >> 2)) * 256 + k0 + (idx & 3) * 8);
      b8[q] = *(const bf16x8*)(BT + (size_t)(by * 128 + (idx >> 2)) * 256 + k0 + (idx & 3) * 8);
    }
    __syncthreads();
#pragma unroll
    for (int q = 0; q < 2; q++) {
      const int idx = q * 256 + t;
      *(bf16x8*)((char*)As + idx * 16) = a8[q];
      *(bf16x8*)((char*)Bs + idx * 16) = b8[q];
    }
    __syncthreads();

    bf16x8 av[4], bv[4];
#pragma unroll
    for (int mt = 0; mt < 4; mt++)
      av[mt] = *(const bf16x8*)&As[(wr * 64 + mt * 16 + lm) * 32 + kq * 8];
#pragma unroll
    for (int nt = 0; nt < 4; nt++)
      bv[nt] = *(const bf16x8*)&Bs[(wc * 64 + nt * 16 + lm) * 32 + kq * 8];
#pragma unroll
    for (int mt = 0; mt < 4; mt++)
#pragma unroll
      for (int nt = 0; nt < 4; nt++)
        acc[mt][nt] = __builtin_amdgcn_mfma_f32_16x16x32_bf16(av[mt], bv[nt], acc[mt][nt], 0, 0, 0);
  }
  const float* resid = by ? xi : xr;
  const float sg = by ? 1.f : -1.f;   // yr: b_r - b_i ; yi: b_r + b_i
#pragma unroll
  for (int mt = 0; mt < 4; mt++)
#pragma unroll
    for (int nt = 0; nt < 4; nt++)
#pragma unroll
      for (int r = 0; r < 4; r++) {
        const int i = m0 + wr * 64 + mt * 16 + kq * 4 + r;
        const int j = wc * 64 + nt * 16 + lm;
        out[(size_t)by * (NN * DD) + (size_t)i * DD + j] =
            acc[mt][nt][r] + br[j] + sg * bi[j] + resid[(size_t)i * DD + j];
      }
}

// ---------------- K5: losses (f32 out) ----------------
__global__ __launch_bounds__(1024) void k_loss(
    const float* __restrict__ thi, const int* __restrict__ tix,
    const float* __restrict__ stats, float* __restrict__ out2)
{
  __shared__ float red[16];
  const int t = threadIdx.x;
  const int idx = tix[t];
  float v = stats[idx * 4 + 2] - stats[idx * 4 + 3];  // logp at label = picked - lse
#pragma unroll
  for (int off = 32; off > 0; off >>= 1) v += __shfl_xor(v, off, 64);
  if ((t & 63) == 0) red[t >> 6] = v;
  __syncthreads();
  if (t == 0) {
    float s = 0.f;
    for (int q = 0; q < 16; q++) s += red[q];
    const float sup = -0.1f * (s / (float)TT);
    float th[CC];
    for (int c = 0; c < CC; c++) th[c] = thi[c];
    for (int a = 1; a < CC; a++) {        // insertion sort ascending
      const float key = th[a];
      int b = a - 1;
      while (b >= 0 && th[b] > key) { th[b + 1] = th[b]; b--; }
      th[b + 1] = key;
    }
    float dsum = 0.f, dmax = 0.f;
    for (int a = 0; a < CC - 1; a++) {
      const float d = fabsf(th[a] - th[a + 1]);
      dsum += d;
      dmax = fmaxf(dmax, d);
    }
    const float difference = dsum / (dmax + 1e-6f);
    out2[0] = 0.1f / (1e-6f + difference);  // separate_loss
    out2[1] = sup;                          // supervised_loss
  }
}

extern "C" void kernel_launch(void* const* d_in, const int* in_sizes, int n_in,
                              void* d_out, int out_size, void* d_ws, size_t ws_size,
                              hipStream_t stream) {
  const float* xr  = (const float*)d_in[0];
  const float* xi  = (const float*)d_in[1];
  const float* adj = (const float*)d_in[2];
  const float* thr = (const float*)d_in[3];
  const float* thi = (const float*)d_in[4];
  const float* Wr  = (const float*)d_in[5];
  const float* br  = (const float*)d_in[6];
  const float* Wi  = (const float*)d_in[7];
  const float* bi  = (const float*)d_in[8];
  const float* Wcr = (const float*)d_in[9];
  const float* bcr = (const float*)d_in[10];
  const float* Wci = (const float*)d_in[11];
  const float* bci = (const float*)d_in[12];
  const int* labels = (const int*)d_in[13];
  const int* tix    = (const int*)d_in[14];
  float* out = (float*)d_out;

  // workspace layout (~12.63 MB):
  //   [0,4MB)        sT [256][8192] bf16; reused as msg [8192][256] bf16 after adj GEMM
  //   [4,12MB)       mbuf [8192][256] f32
  //   [12MB,+128KB)  stats [8192][4] f32
  //   [+256KB,+384KB) BT [256][256] bf16
  char* ws = (char*)d_ws;
  __hip_bfloat16* sT   = (__hip_bfloat16*)(ws);
  float*          mbuf = (float*)(ws + (size_t)4 * 1024 * 1024);
  float*          stats= (float*)(ws + (size_t)12 * 1024 * 1024);
  __hip_bfloat16* BT   = (__hip_bfloat16*)(ws + (size_t)12 * 1024 * 1024 + 256 * 1024);
  __hip_bfloat16* msg  = sT;   // sT dead after k_adj_gemm

  hipMemsetAsync(mbuf, 0, (size_t)NN * 256 * sizeof(float), stream);
  k_head<<<NN / 4, 256, 0, stream>>>(xr, xi, Wcr, bcr, Wci, bci, thr, thi, labels, sT, stats);
  k_build_bt<<<256, 256, 0, stream>>>(Wr, Wi, BT);
  k_adj_gemm<<<dim3(128, 4), 256, 0, stream>>>(adj, sT, mbuf);
  k_msg<<<NN * DD / 256, 256, 0, stream>>>(mbuf, stats, msg);
  k_mlp<<<dim3(64, 2), 256, 0, stream>>>(msg, BT, br, bi, xr, xi, out);
  k_loss<<<1, TT, 0, stream>>>(thi, tix, stats, out + (size_t)2 * NN * DD);
}

// Round 4
// 499.438 us; speedup vs baseline: 1.0278x; 1.0278x over previous
//
#include <hip/hip_runtime.h>
#include <hip/hip_bf16.h>

#define NN 8192
#define DD 128
#define CC 10
#define TT 1024

typedef __attribute__((ext_vector_type(8))) short bf16x8;   // 8 bf16 in 4 VGPRs
typedef __attribute__((ext_vector_type(4))) short bf16x4;   // 4 bf16 in 2 VGPRs
typedef __attribute__((ext_vector_type(4))) float f32x4;

__device__ __forceinline__ void gload16(const void* g, void* l) {
  __builtin_amdgcn_global_load_lds(
      (const __attribute__((address_space(1))) void*)g,
      (__attribute__((address_space(3))) void*)l, 16, 0, 0);
}

__device__ __forceinline__ bf16x4 cvt4(float a, float b, float c, float d) {
  __hip_bfloat16 t[4] = {__float2bfloat16(a), __float2bfloat16(b),
                         __float2bfloat16(c), __float2bfloat16(d)};
  return *(const bf16x4*)t;
}

// ---------------- K1: class head + softmax + coefficients + s row-major ----------------
// one wave per node; s[node][256] = [s_r | s_i], coalesced writes
__global__ __launch_bounds__(256) void k_head(
    const float* __restrict__ xr, const float* __restrict__ xi,
    const float* __restrict__ Wcr, const float* __restrict__ bcr,
    const float* __restrict__ Wci, const float* __restrict__ bci,
    const float* __restrict__ thr, const float* __restrict__ thi,
    const int* __restrict__ labels,
    __hip_bfloat16* __restrict__ s,       // [8192][256] bf16
    float* __restrict__ stats)            // [8192][4] = inr, ini, picked, lse
{
  const int lane = threadIdx.x & 63;
  const int i = blockIdx.x * 4 + (threadIdx.x >> 6);

  const float xr0 = xr[(size_t)i * DD + lane];
  const float xr1 = xr[(size_t)i * DD + 64 + lane];
  const float xi0 = xi[(size_t)i * DD + lane];
  const float xi1 = xi[(size_t)i * DD + 64 + lane];

  float pn[CC];
#pragma unroll
  for (int c = 0; c < CC; c++) {
    const float wr0 = Wcr[c * DD + lane];
    const float wr1 = Wcr[c * DD + 64 + lane];
    const float wi0 = Wci[c * DD + lane];
    const float wi1 = Wci[c * DD + 64 + lane];
    float pa = xr0 * wr0 + xr1 * wr1;   // xr . Wc_r[c]
    float pb = xi0 * wr0 + xi1 * wr1;   // xi . Wc_r[c]
    float pc = xi0 * wi0 + xi1 * wi1;   // xi . Wc_i[c]
    float pd = xr0 * wi0 + xr1 * wi1;   // xr . Wc_i[c]
#pragma unroll
    for (int off = 32; off > 0; off >>= 1) {
      pa += __shfl_xor(pa, off, 64);
      pb += __shfl_xor(pb, off, 64);
      pc += __shfl_xor(pc, off, 64);
      pd += __shfl_xor(pd, off, 64);
    }
    const float cr = (pa + bcr[c]) - (pc + bci[c]);
    const float ci = (pb + bcr[c]) + (pd + bci[c]);
    pn[c] = sqrtf(cr * cr + ci * ci);
  }
  float mx = pn[0];
#pragma unroll
  for (int c = 1; c < CC; c++) mx = fmaxf(mx, pn[c]);
  float ex[CC];
  float den = 0.f;
#pragma unroll
  for (int c = 0; c < CC; c++) { ex[c] = expf(pn[c] - mx); den += ex[c]; }
  float inr = 0.f, ini = 0.f;
#pragma unroll
  for (int c = 0; c < CC; c++) {
    const float sm = ex[c] / den;
    inr += sm * thr[c];
    ini += sm * thi[c];
  }
  // out = conj(in):  s_r = in_r*xr + in_i*xi ; s_i = in_r*xi - in_i*xr
  s[(size_t)i * 256 + lane]       = __float2bfloat16(inr * xr0 + ini * xi0);
  s[(size_t)i * 256 + 64 + lane]  = __float2bfloat16(inr * xr1 + ini * xi1);
  s[(size_t)i * 256 + 128 + lane] = __float2bfloat16(inr * xi0 - ini * xr0);
  s[(size_t)i * 256 + 192 + lane] = __float2bfloat16(inr * xi1 - ini * xr1);

  if (lane == 0) {
    const int lab = labels[i];
    float picked = pn[0];
#pragma unroll
    for (int c = 1; c < CC; c++) picked = (lab == c) ? pn[c] : picked;
    stats[i * 4 + 0] = inr;
    stats[i * 4 + 1] = ini;
    stats[i * 4 + 2] = picked;
    stats[i * 4 + 3] = mx + logf(den);
  }
}

// ---------------- K1b: tiled transpose s[8192][256] -> sT[256][8192] ----------------
__global__ __launch_bounds__(256) void k_transpose(
    const __hip_bfloat16* __restrict__ s, __hip_bfloat16* __restrict__ sT)
{
  __shared__ __hip_bfloat16 tile[64][72];   // +8 pad breaks bank alignment
  const int t = threadIdx.x;
  const int n0 = blockIdx.x * 64, f0 = blockIdx.y * 64;
  const int r = t >> 2, c = t & 3;
  const bf16x8 v0 = *(const bf16x8*)(s + (size_t)(n0 + r) * 256 + f0 + c * 16);
  const bf16x8 v1 = *(const bf16x8*)(s + (size_t)(n0 + r) * 256 + f0 + c * 16 + 8);
  *(bf16x8*)&tile[r][c * 16] = v0;
  *(bf16x8*)&tile[r][c * 16 + 8] = v1;
  __syncthreads();
  const int fr = t >> 2, nc = t & 3;
  __hip_bfloat16 o[16];
#pragma unroll
  for (int j = 0; j < 16; j++) o[j] = tile[nc * 16 + j][fr];
  *(bf16x8*)(sT + (size_t)(f0 + fr) * NN + n0 + nc * 16) = *(const bf16x8*)&o[0];
  *(bf16x8*)(sT + (size_t)(f0 + fr) * NN + n0 + nc * 16 + 8) = *(const bf16x8*)&o[8];
}

// ---------------- K2: build combined MLP weight, transposed, bf16 ----------------
__global__ __launch_bounds__(256) void k_build_bt(
    const float* __restrict__ Wr, const float* __restrict__ Wi,
    __hip_bfloat16* __restrict__ BT)
{
  const int tid = blockIdx.x * 256 + threadIdx.x;  // 65536
  const int n = tid >> 8, k = tid & 255;
  float v;
  if (n < 128) {
    v = (k < 128) ? Wr[n * 128 + k] : -Wi[n * 128 + (k - 128)];
  } else {
    v = (k < 128) ? Wi[(n - 128) * 128 + k] : Wr[(n - 128) * 128 + (k - 128)];
  }
  BT[tid] = __float2bfloat16(v);
}

// ---------------- K3: part[split] = adj_chunk @ s  (MFMA, BK=64, plain stores) ------
// block tile 64x256, 4 waves each 64x64; grid (128 mtiles, 4 ksplit)
// As: [2][64][32] bf16 (m97-proven 64B-row layout), VGPR-staged with inline f32->bf16.
// Bs: [2][256][32] bf16, async global_load_lds width-16.
__global__ __launch_bounds__(256) void k_adj_gemm(
    const float* __restrict__ adj,            // [8192][8192] f32
    const __hip_bfloat16* __restrict__ sT,    // [256][8192] bf16
    float* __restrict__ part)                 // [4][8192][256] f32
{
  __shared__ __align__(16) __hip_bfloat16 As[2 * 64 * 32];    // 8 KB
  __shared__ __align__(16) __hip_bfloat16 Bs[2 * 256 * 32];   // 32 KB
  const int t = threadIdx.x;
  const int w = t >> 6;
  const int lane = t & 63;
  const int lm = lane & 15;
  const int kq = lane >> 4;
  const int m0 = blockIdx.x * 64;
  const int kbase = blockIdx.y * 2048;

  // A staging map: thread t covers (ks=q, row=t>>2, ch2=t&3), 8 consecutive f32
  const float* adjp = adj + (size_t)(m0 + (t >> 2)) * NN + kbase + (t & 3) * 8;
  // B staging map: chunk p = q*256+t -> ks=p>>10, row=(p>>2)&255, kqslot=p&3
  const __hip_bfloat16* srcB[8];
#pragma unroll
  for (int q = 0; q < 8; q++) {
    const int p = q * 256 + t;
    srcB[q] = sT + (size_t)((p >> 2) & 255) * NN + kbase + (p >> 10) * 32 + (p & 3) * 8;
  }

  f32x4 acc[4][4];
#pragma unroll
  for (int a = 0; a < 4; a++)
#pragma unroll
    for (int b = 0; b < 4; b++) acc[a][b] = (f32x4){0.f, 0.f, 0.f, 0.f};

  for (int kt = 0; kt < 32; kt++) {
    const int koff = kt * 64;
    // adj -> regs (f32), overlaps previous iteration's MFMA
    float4 f0a = *(const float4*)(adjp + koff);
    float4 f0b = *(const float4*)(adjp + koff + 4);
    float4 f1a = *(const float4*)(adjp + koff + 32);
    float4 f1b = *(const float4*)(adjp + koff + 36);
    __syncthreads();   // all waves done reading LDS from previous iteration
    // As writes: contiguous b128 per thread per ks
    {
      bf16x4 c0 = cvt4(f0a.x, f0a.y, f0a.z, f0a.w);
      bf16x4 c1 = cvt4(f0b.x, f0b.y, f0b.z, f0b.w);
      bf16x4 c2 = cvt4(f1a.x, f1a.y, f1a.z, f1a.w);
      bf16x4 c3 = cvt4(f1b.x, f1b.y, f1b.z, f1b.w);
      *(bf16x4*)&As[t * 8] = c0;
      *(bf16x4*)&As[t * 8 + 4] = c1;
      *(bf16x4*)&As[2048 + t * 8] = c2;
      *(bf16x4*)&As[2048 + t * 8 + 4] = c3;
    }
    // Bs: async global->LDS, wave-uniform base + lane*16
#pragma unroll
    for (int q = 0; q < 8; q++)
      gload16(srcB[q] + koff, (char*)Bs + (q * 256 + t) * 16);
    __syncthreads();   // drains vmcnt+lgkm: As visible, Bs complete

#pragma unroll
    for (int ks = 0; ks < 2; ks++) {
      bf16x8 av[4], bv[4];
#pragma unroll
      for (int mt = 0; mt < 4; mt++)
        av[mt] = *(const bf16x8*)&As[(ks * 64 + mt * 16 + lm) * 32 + kq * 8];
#pragma unroll
      for (int nt = 0; nt < 4; nt++)
        bv[nt] = *(const bf16x8*)&Bs[(ks * 256 + w * 64 + nt * 16 + lm) * 32 + kq * 8];
#pragma unroll
      for (int mt = 0; mt < 4; mt++)
#pragma unroll
        for (int nt = 0; nt < 4; nt++)
          acc[mt][nt] = __builtin_amdgcn_mfma_f32_16x16x32_bf16(av[mt], bv[nt], acc[mt][nt], 0, 0, 0);
    }
  }
  // C/D layout: col = lane&15, row = (lane>>4)*4 + reg  [m89-verified]
  float* po = part + (size_t)blockIdx.y * NN * 256;
#pragma unroll
  for (int mt = 0; mt < 4; mt++)
#pragma unroll
    for (int nt = 0; nt < 4; nt++)
#pragma unroll
      for (int r = 0; r < 4; r++) {
        const int row = m0 + mt * 16 + kq * 4 + r;
        const int col = w * 64 + nt * 16 + lm;
        po[(size_t)row * 256 + col] = acc[mt][nt][r];
      }
}

// ---------------- K4a: reduce 4 split-K partials + complex scale -> msg bf16 --------
__global__ __launch_bounds__(256) void k_msg(
    const float* __restrict__ part, const float* __restrict__ stats,
    __hip_bfloat16* __restrict__ msg)   // [8192][256] = [msg_r | msg_i] bf16
{
  const int tid = blockIdx.x * 256 + threadIdx.x;  // 8192*32
  const int i = tid >> 5, c4 = tid & 31;           // 4 cols per thread
  const size_t base = (size_t)i * 256 + c4 * 4;
  float4 ar = {0.f, 0.f, 0.f, 0.f}, ai = {0.f, 0.f, 0.f, 0.f};
#pragma unroll
  for (int sp = 0; sp < 4; sp++) {
    const float4 pr = *(const float4*)(part + (size_t)sp * NN * 256 + base);
    const float4 pi = *(const float4*)(part + (size_t)sp * NN * 256 + base + 128);
    ar.x += pr.x; ar.y += pr.y; ar.z += pr.z; ar.w += pr.w;
    ai.x += pi.x; ai.y += pi.y; ai.z += pi.z; ai.w += pi.w;
  }
  const float inr = stats[i * 4 + 0], ini = stats[i * 4 + 1];
  bf16x4 mr = cvt4(inr * ar.x - ini * ai.x, inr * ar.y - ini * ai.y,
                   inr * ar.z - ini * ai.z, inr * ar.w - ini * ai.w);
  bf16x4 mi = cvt4(inr * ai.x + ini * ar.x, inr * ai.y + ini * ar.y,
                   inr * ai.z + ini * ar.z, inr * ai.w + ini * ar.w);
  *(bf16x4*)(msg + base) = mr;
  *(bf16x4*)(msg + base + 128) = mi;
}

// ---------------- K4b: MLP GEMM + bias + residual -> out (f32) ----------------
// grid (128 mtiles, 2 col halves); block tile 64x128; K=256, BK=32; all-async staging
__global__ __launch_bounds__(256) void k_mlp(
    const __hip_bfloat16* __restrict__ msg,  // [8192][256] bf16
    const __hip_bfloat16* __restrict__ BT,   // [256][256] bf16
    const float* __restrict__ br, const float* __restrict__ bi,
    const float* __restrict__ xr, const float* __restrict__ xi,
    float* __restrict__ out)                 // new_r @0, new_i @ NN*DD (f32)
{
  __shared__ __align__(16) __hip_bfloat16 As[64 * 32];    // 4 KB
  __shared__ __align__(16) __hip_bfloat16 Bs[128 * 32];   // 8 KB
  const int t = threadIdx.x;
  const int w = t >> 6;
  const int lane = t & 63;
  const int lm = lane & 15, kq = lane >> 4;
  const int m0 = blockIdx.x * 64;
  const int by = blockIdx.y;

  const __hip_bfloat16* srcA = msg + (size_t)(m0 + (t >> 2)) * 256 + (t & 3) * 8;
  const __hip_bfloat16* srcB0 = BT + (size_t)(by * 128 + (t >> 2)) * 256 + (t & 3) * 8;
  const __hip_bfloat16* srcB1 = BT + (size_t)(by * 128 + 64 + (t >> 2)) * 256 + (t & 3) * 8;

  f32x4 acc[4][2];
#pragma unroll
  for (int a = 0; a < 4; a++)
#pragma unroll
    for (int b = 0; b < 2; b++) acc[a][b] = (f32x4){0.f, 0.f, 0.f, 0.f};

  for (int kt = 0; kt < 8; kt++) {
    const int koff = kt * 32;
    __syncthreads();
    gload16(srcA + koff, (char*)As + t * 16);
    gload16(srcB0 + koff, (char*)Bs + t * 16);
    gload16(srcB1 + koff, (char*)Bs + (256 + t) * 16);
    __syncthreads();

    bf16x8 av[4], bv[2];
#pragma unroll
    for (int mt = 0; mt < 4; mt++)
      av[mt] = *(const bf16x8*)&As[(mt * 16 + lm) * 32 + kq * 8];
#pragma unroll
    for (int nt = 0; nt < 2; nt++)
      bv[nt] = *(const bf16x8*)&Bs[(w * 32 + nt * 16 + lm) * 32 + kq * 8];
#pragma unroll
    for (int mt = 0; mt < 4; mt++)
#pragma unroll
      for (int nt = 0; nt < 2; nt++)
        acc[mt][nt] = __builtin_amdgcn_mfma_f32_16x16x32_bf16(av[mt], bv[nt], acc[mt][nt], 0, 0, 0);
  }
  const float* resid = by ? xi : xr;
  const float sg = by ? 1.f : -1.f;   // yr: b_r - b_i ; yi: b_r + b_i
#pragma unroll
  for (int mt = 0; mt < 4; mt++)
#pragma unroll
    for (int nt = 0; nt < 2; nt++)
#pragma unroll
      for (int r = 0; r < 4; r++) {
        const int i = m0 + mt * 16 + kq * 4 + r;
        const int j = w * 32 + nt * 16 + lm;
        out[(size_t)by * (NN * DD) + (size_t)i * DD + j] =
            acc[mt][nt][r] + br[j] + sg * bi[j] + resid[(size_t)i * DD + j];
      }
}

// ---------------- K5: losses (f32 out) ----------------
__global__ __launch_bounds__(1024) void k_loss(
    const float* __restrict__ thi, const int* __restrict__ tix,
    const float* __restrict__ stats, float* __restrict__ out2)
{
  __shared__ float red[16];
  const int t = threadIdx.x;
  const int idx = tix[t];
  float v = stats[idx * 4 + 2] - stats[idx * 4 + 3];  // logp at label = picked - lse
#pragma unroll
  for (int off = 32; off > 0; off >>= 1) v += __shfl_xor(v, off, 64);
  if ((t & 63) == 0) red[t >> 6] = v;
  __syncthreads();
  if (t == 0) {
    float s = 0.f;
    for (int q = 0; q < 16; q++) s += red[q];
    const float sup = -0.1f * (s / (float)TT);
    float th[CC];
    for (int c = 0; c < CC; c++) th[c] = thi[c];
    for (int a = 1; a < CC; a++) {        // insertion sort ascending
      const float key = th[a];
      int b = a - 1;
      while (b >= 0 && th[b] > key) { th[b + 1] = th[b]; b--; }
      th[b + 1] = key;
    }
    float dsum = 0.f, dmax = 0.f;
    for (int a = 0; a < CC - 1; a++) {
      const float d = fabsf(th[a] - th[a + 1]);
      dsum += d;
      dmax = fmaxf(dmax, d);
    }
    const float difference = dsum / (dmax + 1e-6f);
    out2[0] = 0.1f / (1e-6f + difference);  // separate_loss
    out2[1] = sup;                          // supervised_loss
  }
}

extern "C" void kernel_launch(void* const* d_in, const int* in_sizes, int n_in,
                              void* d_out, int out_size, void* d_ws, size_t ws_size,
                              hipStream_t stream) {
  const float* xr  = (const float*)d_in[0];
  const float* xi  = (const float*)d_in[1];
  const float* adj = (const float*)d_in[2];
  const float* thr = (const float*)d_in[3];
  const float* thi = (const float*)d_in[4];
  const float* Wr  = (const float*)d_in[5];
  const float* br  = (const float*)d_in[6];
  const float* Wi  = (const float*)d_in[7];
  const float* bi  = (const float*)d_in[8];
  const float* Wcr = (const float*)d_in[9];
  const float* bcr = (const float*)d_in[10];
  const float* Wci = (const float*)d_in[11];
  const float* bci = (const float*)d_in[12];
  const int* labels = (const int*)d_in[13];
  const int* tix    = (const int*)d_in[14];
  float* out = (float*)d_out;

  // workspace layout (~40.4 MB):
  //   [0,4MB)     s [8192][256] bf16 (row-major); reused as msg after k_transpose
  //   [4,8MB)     sT [256][8192] bf16
  //   [8,40MB)    part [4][8192][256] f32
  //   [40MB,+128K)  stats [8192][4] f32
  //   [40MB+128K,+128K) BT [256][256] bf16
  char* ws = (char*)d_ws;
  __hip_bfloat16* s    = (__hip_bfloat16*)(ws);
  __hip_bfloat16* sT   = (__hip_bfloat16*)(ws + (size_t)4 * 1024 * 1024);
  float*          part = (float*)(ws + (size_t)8 * 1024 * 1024);
  float*          stats= (float*)(ws + (size_t)40 * 1024 * 1024);
  __hip_bfloat16* BT   = (__hip_bfloat16*)(ws + (size_t)40 * 1024 * 1024 + 131072);
  __hip_bfloat16* msg  = s;   // s dead after k_transpose

  k_head<<<NN / 4, 256, 0, stream>>>(xr, xi, Wcr, bcr, Wci, bci, thr, thi, labels, s, stats);
  k_transpose<<<dim3(NN / 64, 4), 256, 0, stream>>>(s, sT);
  k_build_bt<<<256, 256, 0, stream>>>(Wr, Wi, BT);
  k_adj_gemm<<<dim3(128, 4), 256, 0, stream>>>(adj, sT, part);
  k_msg<<<NN * 32 / 256, 256, 0, stream>>>(part, stats, msg);
  k_mlp<<<dim3(128, 2), 256, 0, stream>>>(msg, BT, br, bi, xr, xi, out);
  k_loss<<<1, TT, 0, stream>>>(thi, tix, stats, out + (size_t)2 * NN * DD);
}